// Round 4
// baseline (919.069 us; speedup 1.0000x reference)
//
#include <hip/hip_runtime.h>
#include <math.h>

#define B_    16384
#define IN_   64
#define DENC_ 512
#define NE_   2048
#define P_    12
#define ROWS_ 196608      // B_*P_
#define BETA_ 0.25

// output layout (all float32, concatenated in return order)
#define XHAT_OFF 1
#define PERP_OFF 1048577   // 1 + 16384*64
#define IDXF_OFF 1048578
#define COEF_OFF 1245186   // IDXF_OFF + 196608

typedef __bf16 bf16x8 __attribute__((ext_vector_type(8)));
typedef float  f32x16 __attribute__((ext_vector_type(16)));

__device__ __forceinline__ void split3(float v, __bf16& h, __bf16& m, __bf16& l) {
    h = (__bf16)v;
    float r1 = v - (float)h;
    m = (__bf16)r1;
    float r2 = r1 - (float)m;
    l = (__bf16)r2;
}

// ---------------------------------------------------------------------------
// Pre-split weights: W[K][N] f32 -> Wt planes [N][K] bf16 (hi/mid/lo).
// ---------------------------------------------------------------------------
__global__ void k_wsplit(const float* __restrict__ W,
                         __bf16* __restrict__ Wh, __bf16* __restrict__ Wm,
                         __bf16* __restrict__ Wl, int kshift, int N, int total) {
    int idx = blockIdx.x * 256 + threadIdx.x;
    if (idx < total) {
        int n = idx >> kshift;
        int k = idx & ((1 << kshift) - 1);
        float v = W[(size_t)k * N + n];
        __bf16 h, m, l;
        split3(v, h, m, l);
        Wh[idx] = h; Wm[idx] = m; Wl[idx] = l;
    }
}

// ---------------------------------------------------------------------------
// MFMA GEMM + bias (3-term split, verified R2) — unchanged from R3
// ---------------------------------------------------------------------------
__global__ __launch_bounds__(256) void k_gemm_mfma(const float* __restrict__ A,
                                                   const __bf16* __restrict__ Bh,
                                                   const __bf16* __restrict__ Bm,
                                                   const __bf16* __restrict__ Bl,
                                                   const float* __restrict__ bias,
                                                   float* __restrict__ C,
                                                   int N, int K) {
    __shared__ __bf16 eS[3][64 * 64];

    const int tid = threadIdx.x;
    const int w = tid >> 6, lane = tid & 63;
    const int r0 = blockIdx.y * 128 + w * 32;
    const int n0 = blockIdx.x * 64;
    const int lrow = lane & 31;
    const int half = lane >> 5;

    f32x16 acc0, acc1;
#pragma unroll
    for (int i = 0; i < 16; ++i) { acc0[i] = 0.0f; acc1[i] = 0.0f; }

    for (int k0 = 0; k0 < K; k0 += 64) {
        __syncthreads();
        {
            const int col = tid >> 3, q = tid & 7;
#pragma unroll
            for (int p = 0; p < 2; ++p) {
                int cc = col + 32 * p;
                int g = q ^ (cc & 7);
                size_t soff = (size_t)(n0 + cc) * K + k0 + q * 8;
                int doff = cc * 64 + g * 8;
                *(float4*)(&eS[0][doff]) = *(const float4*)(Bh + soff);
                *(float4*)(&eS[1][doff]) = *(const float4*)(Bm + soff);
                *(float4*)(&eS[2][doff]) = *(const float4*)(Bl + soff);
            }
        }
        __syncthreads();

        bf16x8 ah[4], am[4], al[4];
        {
            const float* ar = A + (size_t)(r0 + lrow) * K + k0 + half * 8;
#pragma unroll
            for (int kc = 0; kc < 4; ++kc) {
                float4 u0 = *(const float4*)(ar + kc * 16);
                float4 u1 = *(const float4*)(ar + kc * 16 + 4);
                float v[8] = {u0.x, u0.y, u0.z, u0.w, u1.x, u1.y, u1.z, u1.w};
#pragma unroll
                for (int j = 0; j < 8; ++j) {
                    __bf16 hh, mm, ll;
                    split3(v[j], hh, mm, ll);
                    ah[kc][j] = hh; am[kc][j] = mm; al[kc][j] = ll;
                }
            }
        }

#pragma unroll
        for (int kc = 0; kc < 4; ++kc) {
            const int q = kc * 2 + half;
            const int g = (q ^ (lrow & 7)) * 8;
            bf16x8 b0h = *(const bf16x8*)(&eS[0][lrow * 64 + g]);
            bf16x8 b0m = *(const bf16x8*)(&eS[1][lrow * 64 + g]);
            bf16x8 b0l = *(const bf16x8*)(&eS[2][lrow * 64 + g]);
            bf16x8 b1h = *(const bf16x8*)(&eS[0][(lrow + 32) * 64 + g]);
            bf16x8 b1m = *(const bf16x8*)(&eS[1][(lrow + 32) * 64 + g]);
            bf16x8 b1l = *(const bf16x8*)(&eS[2][(lrow + 32) * 64 + g]);

            acc0 = __builtin_amdgcn_mfma_f32_32x32x16_bf16(ah[kc], b0h, acc0, 0, 0, 0);
            acc1 = __builtin_amdgcn_mfma_f32_32x32x16_bf16(ah[kc], b1h, acc1, 0, 0, 0);
            acc0 = __builtin_amdgcn_mfma_f32_32x32x16_bf16(ah[kc], b0m, acc0, 0, 0, 0);
            acc1 = __builtin_amdgcn_mfma_f32_32x32x16_bf16(ah[kc], b1m, acc1, 0, 0, 0);
            acc0 = __builtin_amdgcn_mfma_f32_32x32x16_bf16(am[kc], b0h, acc0, 0, 0, 0);
            acc1 = __builtin_amdgcn_mfma_f32_32x32x16_bf16(am[kc], b1h, acc1, 0, 0, 0);
            acc0 = __builtin_amdgcn_mfma_f32_32x32x16_bf16(ah[kc], b0l, acc0, 0, 0, 0);
            acc1 = __builtin_amdgcn_mfma_f32_32x32x16_bf16(ah[kc], b1l, acc1, 0, 0, 0);
            acc0 = __builtin_amdgcn_mfma_f32_32x32x16_bf16(am[kc], b0m, acc0, 0, 0, 0);
            acc1 = __builtin_amdgcn_mfma_f32_32x32x16_bf16(am[kc], b1m, acc1, 0, 0, 0);
            acc0 = __builtin_amdgcn_mfma_f32_32x32x16_bf16(al[kc], b0h, acc0, 0, 0, 0);
            acc1 = __builtin_amdgcn_mfma_f32_32x32x16_bf16(al[kc], b1h, acc1, 0, 0, 0);
        }
    }

    const int col0 = n0 + lrow, col1 = col0 + 32;
    const float bv0 = bias[col0], bv1 = bias[col1];
#pragma unroll
    for (int r = 0; r < 16; ++r) {
        int row = r0 + (r & 3) + 8 * (r >> 2) + 4 * half;
        C[(size_t)row * N + col0] = acc0[r] + bv0;
        C[(size_t)row * N + col1] = acc1[r] + bv1;
    }
}

// ---------------------------------------------------------------------------
// h = h + relu(layer_norm(t) * g + beta)
// ---------------------------------------------------------------------------
__global__ __launch_bounds__(256) void k_lnrelu(const float* __restrict__ t,
                                                float* __restrict__ h,
                                                const float* __restrict__ g,
                                                const float* __restrict__ beta) {
    const int tid = threadIdx.x;
    const int wv = tid >> 6, lane = tid & 63;
    const int row = blockIdx.x * 4 + wv;
    const float* tr = t + (size_t)row * DENC_;
    float* hr = h + (size_t)row * DENC_;

    float4 v0 = *(const float4*)(tr + lane * 4);
    float4 v1 = *(const float4*)(tr + 256 + lane * 4);

    float s = v0.x + v0.y + v0.z + v0.w + v1.x + v1.y + v1.z + v1.w;
#pragma unroll
    for (int m = 1; m < 64; m <<= 1) s += __shfl_xor(s, m);
    float mu = s / 512.0f;

    float d0x = v0.x - mu, d0y = v0.y - mu, d0z = v0.z - mu, d0w = v0.w - mu;
    float d1x = v1.x - mu, d1y = v1.y - mu, d1z = v1.z - mu, d1w = v1.w - mu;
    float vs = d0x * d0x + d0y * d0y + d0z * d0z + d0w * d0w +
               d1x * d1x + d1y * d1y + d1z * d1z + d1w * d1w;
#pragma unroll
    for (int m = 1; m < 64; m <<= 1) vs += __shfl_xor(vs, m);
    float var = vs / 512.0f;
    float rs = (float)(1.0 / sqrt((double)var + 1e-5));

    float4 g0 = *(const float4*)(g + lane * 4);
    float4 g1 = *(const float4*)(g + 256 + lane * 4);
    float4 b0 = *(const float4*)(beta + lane * 4);
    float4 b1 = *(const float4*)(beta + 256 + lane * 4);

    float4 h0 = *(float4*)(hr + lane * 4);
    float4 h1 = *(float4*)(hr + 256 + lane * 4);

    h0.x += fmaxf(d0x * rs * g0.x + b0.x, 0.0f);
    h0.y += fmaxf(d0y * rs * g0.y + b0.y, 0.0f);
    h0.z += fmaxf(d0z * rs * g0.z + b0.z, 0.0f);
    h0.w += fmaxf(d0w * rs * g0.w + b0.w, 0.0f);
    h1.x += fmaxf(d1x * rs * g1.x + b1.x, 0.0f);
    h1.y += fmaxf(d1y * rs * g1.y + b1.y, 0.0f);
    h1.z += fmaxf(d1z * rs * g1.z + b1.z, 0.0f);
    h1.w += fmaxf(d1w * rs * g1.w + b1.w, 0.0f);

    *(float4*)(hr + lane * 4) = h0;
    *(float4*)(hr + 256 + lane * 4) = h1;
}

// ---------------------------------------------------------------------------
// Coalesced codebook split (one wave per codeword). se computed separately
// (k_esq) to preserve R3's exact f32 association.
// ---------------------------------------------------------------------------
__global__ __launch_bounds__(256) void k_esplit_fast(const float* __restrict__ emb,
                                                     __bf16* __restrict__ Ehi,
                                                     __bf16* __restrict__ Emid,
                                                     __bf16* __restrict__ Elo) {
    const int wv = threadIdx.x >> 6, lane = threadIdx.x & 63;
    const int c = blockIdx.x * 4 + wv;
    float v = emb[(size_t)c * 64 + lane];
    __bf16 h, m, l;
    split3(v, h, m, l);
    Ehi[(size_t)c * 64 + lane] = h;
    Emid[(size_t)c * 64 + lane] = m;
    Elo[(size_t)c * 64 + lane] = l;
}

__global__ void k_esq(const float* __restrict__ emb, float* __restrict__ se) {
    int t = blockIdx.x * 256 + threadIdx.x;
    if (t < NE_) {
        float s = 0.0f;
        for (int k = 0; k < 64; ++k) {
            float v = emb[(size_t)t * 64 + k];
            s += v * v;
        }
        se[t] = s;
    }
}

// ---------------------------------------------------------------------------
// sz[row] = sum(z[row]^2)  (association unchanged from R2/R3)
// ---------------------------------------------------------------------------
__global__ __launch_bounds__(256) void k_rowsq(const float* __restrict__ z,
                                               float* __restrict__ sz) {
    const int tid = threadIdx.x;
    const int row = blockIdx.x * 64 + (tid >> 2);
    const int part = tid & 3;
    const float4* zp = (const float4*)(z + (size_t)row * 64) + part * 4;
    float s = 0.0f;
#pragma unroll
    for (int i = 0; i < 4; ++i) {
        float4 v = zp[i];
        s += v.x * v.x + v.y * v.y + v.z * v.z + v.w * v.w;
    }
    s += __shfl_xor(s, 1);
    s += __shfl_xor(s, 2);
    if (part == 0) sz[row] = s;
}

// ---------------------------------------------------------------------------
// MFMA distance + argmin, 64 rows/wave (2 row-groups share every B-fragment),
// sequential col-halves (2 live accumulators). Numerics identical to R1-R3:
// d = fmaf(-2, dot, sz+se), first-index ties.
// ---------------------------------------------------------------------------
__global__ __launch_bounds__(256) void k_distm(const float* __restrict__ z,
                                               const float* __restrict__ se,
                                               const float* __restrict__ sz,
                                               const __bf16* __restrict__ Ehi,
                                               const __bf16* __restrict__ Emid,
                                               const __bf16* __restrict__ Elo,
                                               int* __restrict__ idxw,
                                               float* __restrict__ idxf,
                                               float* __restrict__ lossacc,
                                               int* __restrict__ counts) {
    __shared__ __bf16 eS[3][64 * 64];

    const int tid = threadIdx.x;
    const int w = tid >> 6, lane = tid & 63;
    const int r0 = blockIdx.x * 256 + w * 64;
    const int lrow = lane & 31;
    const int half = lane >> 5;

    // persistent A fragments: 2 row-groups x 3 planes x 4 k-chunks
    bf16x8 ah[2][4], am[2][4], al[2][4];
#pragma unroll
    for (int rg = 0; rg < 2; ++rg) {
        const float* zr = z + (size_t)(r0 + rg * 32 + lrow) * 64 + half * 8;
#pragma unroll
        for (int kc = 0; kc < 4; ++kc) {
            float4 u0 = *(const float4*)(zr + kc * 16);
            float4 u1 = *(const float4*)(zr + kc * 16 + 4);
            float v[8] = {u0.x, u0.y, u0.z, u0.w, u1.x, u1.y, u1.z, u1.w};
#pragma unroll
            for (int j = 0; j < 8; ++j) {
                __bf16 hh, mm, ll;
                split3(v[j], hh, mm, ll);
                ah[rg][kc][j] = hh; am[rg][kc][j] = mm; al[rg][kc][j] = ll;
            }
        }
    }

    float szv[2][16];
#pragma unroll
    for (int rg = 0; rg < 2; ++rg)
#pragma unroll
        for (int r = 0; r < 16; ++r) {
            int rl = (r & 3) + 8 * (r >> 2) + 4 * half;
            szv[rg][r] = sz[r0 + rg * 32 + rl];
        }

    float bd[2][16];
    int bi[2][16];
#pragma unroll
    for (int rg = 0; rg < 2; ++rg)
#pragma unroll
        for (int r = 0; r < 16; ++r) { bd[rg][r] = 1e30f; bi[rg][r] = 0; }

    for (int ch32 = 0; ch32 < 32; ++ch32) {
        const int c0 = ch32 * 64;
        __syncthreads();
        {
            const int col = tid >> 3, q = tid & 7;
#pragma unroll
            for (int p = 0; p < 2; ++p) {
                int cc = col + 32 * p;
                int g = q ^ (cc & 7);
                size_t soff = (size_t)(c0 + cc) * 64 + q * 8;
                int doff = cc * 64 + g * 8;
                *(float4*)(&eS[0][doff]) = *(const float4*)(Ehi + soff);
                *(float4*)(&eS[1][doff]) = *(const float4*)(Emid + soff);
                *(float4*)(&eS[2][doff]) = *(const float4*)(Elo + soff);
            }
        }
        __syncthreads();

#pragma unroll
        for (int ch = 0; ch < 2; ++ch) {
            f32x16 acc0, acc1;
#pragma unroll
            for (int i = 0; i < 16; ++i) { acc0[i] = 0.0f; acc1[i] = 0.0f; }

            const int cL = ch * 32 + lrow;
#pragma unroll
            for (int kc = 0; kc < 4; ++kc) {
                const int q = kc * 2 + half;
                const int base = cL * 64 + (q ^ (cL & 7)) * 8;
                bf16x8 bh = *(const bf16x8*)(&eS[0][base]);
                acc0 = __builtin_amdgcn_mfma_f32_32x32x16_bf16(ah[0][kc], bh, acc0, 0, 0, 0);
                acc1 = __builtin_amdgcn_mfma_f32_32x32x16_bf16(ah[1][kc], bh, acc1, 0, 0, 0);
                acc0 = __builtin_amdgcn_mfma_f32_32x32x16_bf16(am[0][kc], bh, acc0, 0, 0, 0);
                acc1 = __builtin_amdgcn_mfma_f32_32x32x16_bf16(am[1][kc], bh, acc1, 0, 0, 0);
                acc0 = __builtin_amdgcn_mfma_f32_32x32x16_bf16(al[0][kc], bh, acc0, 0, 0, 0);
                acc1 = __builtin_amdgcn_mfma_f32_32x32x16_bf16(al[1][kc], bh, acc1, 0, 0, 0);
                bf16x8 bm = *(const bf16x8*)(&eS[1][base]);
                acc0 = __builtin_amdgcn_mfma_f32_32x32x16_bf16(ah[0][kc], bm, acc0, 0, 0, 0);
                acc1 = __builtin_amdgcn_mfma_f32_32x32x16_bf16(ah[1][kc], bm, acc1, 0, 0, 0);
                acc0 = __builtin_amdgcn_mfma_f32_32x32x16_bf16(am[0][kc], bm, acc0, 0, 0, 0);
                acc1 = __builtin_amdgcn_mfma_f32_32x32x16_bf16(am[1][kc], bm, acc1, 0, 0, 0);
                bf16x8 bl = *(const bf16x8*)(&eS[2][base]);
                acc0 = __builtin_amdgcn_mfma_f32_32x32x16_bf16(ah[0][kc], bl, acc0, 0, 0, 0);
                acc1 = __builtin_amdgcn_mfma_f32_32x32x16_bf16(ah[1][kc], bl, acc1, 0, 0, 0);
            }

            const int c = c0 + cL;
            const float sec = se[c];
#pragma unroll
            for (int r = 0; r < 16; ++r) {
                float d0 = fmaf(-2.0f, acc0[r], szv[0][r] + sec);
                if (d0 < bd[0][r]) { bd[0][r] = d0; bi[0][r] = c; }
                float d1 = fmaf(-2.0f, acc1[r], szv[1][r] + sec);
                if (d1 < bd[1][r]) { bd[1][r] = d1; bi[1][r] = c; }
            }
        }
    }

    // cross-lane argmin within each 32-lane half (lexicographic: d, then idx)
#pragma unroll
    for (int rg = 0; rg < 2; ++rg)
#pragma unroll
        for (int r = 0; r < 16; ++r) {
            float d = bd[rg][r];
            int i = bi[rg][r];
#pragma unroll
            for (int off = 1; off < 32; off <<= 1) {
                float od = __shfl_xor(d, off);
                int oi = __shfl_xor(i, off);
                if (od < d || (od == d && oi < i)) { d = od; i = oi; }
            }
            bd[rg][r] = d; bi[rg][r] = i;
        }

    if (lrow == 0) {
        float lsum = 0.0f;
#pragma unroll
        for (int rg = 0; rg < 2; ++rg)
#pragma unroll
            for (int r = 0; r < 16; ++r) {
                int rl = (r & 3) + 8 * (r >> 2) + 4 * half;
                int row = r0 + rg * 32 + rl;
                idxw[row] = bi[rg][r];
                idxf[row] = (float)bi[rg][r];
                lsum += bd[rg][r];
                atomicAdd(&counts[bi[rg][r]], 1);
            }
        atomicAdd(lossacc, lsum);
    }
}

// ---------------------------------------------------------------------------
// loss (from accumulated dmin sum) + perplexity (from counts)
// ---------------------------------------------------------------------------
__global__ __launch_bounds__(256) void k_lossperp(const float* __restrict__ lossacc,
                                                  const int* __restrict__ counts,
                                                  float* __restrict__ out) {
    __shared__ double red[256];
    const int tid = threadIdx.x;

    double hsum = 0.0;
    for (int i = tid; i < NE_; i += 256) {
        float p = (float)counts[i] / 196608.0f;
        float lg = logf(p + 1e-10f);
        hsum += (double)(p * lg);
    }
    red[tid] = hsum;
    __syncthreads();
    for (int off = 128; off > 0; off >>= 1) {
        if (tid < off) red[tid] += red[tid + off];
        __syncthreads();
    }
    if (tid == 0) {
        out[PERP_OFF] = (float)exp(-red[0]);
        out[0] = (float)((double)lossacc[0] * (1.0 + BETA_) / ((double)ROWS_ * IN_));
    }
}

// ---------------------------------------------------------------------------
// per-block pinv least-squares: coeff + x_hat (dedup -> min-norm, f64 Cholesky)
// ---------------------------------------------------------------------------
__global__ __launch_bounds__(256) void k_pinv(const float* __restrict__ xin,
                                              const float* __restrict__ emb,
                                              const int* __restrict__ idxw,
                                              float* __restrict__ coeff,
                                              float* __restrict__ xhat) {
    __shared__ float aS[4][12][65];
    __shared__ float xS[4][64];
    __shared__ double GS[4][12][12];
    __shared__ double bS[4][12];
    __shared__ double uS[4][12];
    __shared__ float cS[4][12];

    const int tid = threadIdx.x;
    const int wv = tid >> 6, lane = tid & 63;
    const int b = blockIdx.x * 4 + wv;

    int my = 0;
    if (lane < 12) my = idxw[(size_t)b * 12 + lane];
    int id[12];
#pragma unroll
    for (int p = 0; p < 12; ++p) id[p] = __shfl(my, p);

    int rep = lane, mcnt = 1;
    if (lane < 12) {
        rep = -1;
        mcnt = 0;
        for (int q = 0; q < 12; ++q) {
            if (id[q] == id[lane]) {
                if (rep < 0) rep = q;
                mcnt++;
            }
        }
    }

#pragma unroll
    for (int p = 0; p < 12; ++p) aS[wv][p][lane] = emb[(size_t)id[p] * 64 + lane];
    xS[wv][lane] = xin[(size_t)b * 64 + lane];
    __syncthreads();

    for (int item = lane; item < 90; item += 64) {
        if (item < 78) {
            int j = 0, k = 0, c = item;
            for (j = 0; j < 12; ++j) {
                int cnt = 12 - j;
                if (c < cnt) { k = j + c; break; }
                c -= cnt;
            }
            double s = 0.0;
            for (int t = 0; t < 64; ++t) s += (double)aS[wv][j][t] * (double)aS[wv][k][t];
            GS[wv][j][k] = s;
            GS[wv][k][j] = s;
        } else {
            int j = item - 78;
            double s = 0.0;
            for (int t = 0; t < 64; ++t) s += (double)aS[wv][j][t] * (double)xS[wv][t];
            bS[wv][j] = s;
        }
    }
    __syncthreads();

    if (lane == 0) {
        for (int p = 0; p < 12; ++p) {
            int rp = -1;
            for (int q = 0; q < 12; ++q) {
                if (id[q] == id[p]) { rp = q; break; }
            }
            if (rp != p) {
                for (int q = 0; q < 12; ++q) {
                    GS[wv][p][q] = 0.0;
                    GS[wv][q][p] = 0.0;
                }
                GS[wv][p][p] = 1.0;
                bS[wv][p] = 0.0;
            }
        }
    }
    __syncthreads();

    for (int j = 0; j < 12; ++j) {
        if (lane == j) {
            double s = GS[wv][j][j];
            for (int k = 0; k < j; ++k) {
                double l = GS[wv][j][k];
                s -= l * l;
            }
            GS[wv][j][j] = sqrt(fmax(s, 1e-30));
        }
        __syncthreads();
        if (lane > j && lane < 12) {
            double s = GS[wv][lane][j];
            for (int k = 0; k < j; ++k) s -= GS[wv][lane][k] * GS[wv][j][k];
            GS[wv][lane][j] = s / GS[wv][j][j];
        }
        __syncthreads();
    }

    if (lane == 0) {
        double y[12];
        for (int i = 0; i < 12; ++i) {
            double s = bS[wv][i];
            for (int k = 0; k < i; ++k) s -= GS[wv][i][k] * y[k];
            y[i] = s / GS[wv][i][i];
        }
        for (int i = 11; i >= 0; --i) {
            double s = y[i];
            for (int k = i + 1; k < 12; ++k) s -= GS[wv][k][i] * uS[wv][k];
            uS[wv][i] = s / GS[wv][i][i];
        }
    }
    __syncthreads();

    if (lane < 12) {
        double c = uS[wv][rep] / (double)mcnt;
        coeff[(size_t)b * 12 + lane] = (float)c;
        cS[wv][lane] = (float)c;
    }
    __syncthreads();

    float s = 0.0f;
#pragma unroll
    for (int p = 0; p < 12; ++p) s += aS[wv][p][lane] * cS[wv][p];
    xhat[(size_t)b * 64 + lane] = s;
}

// ---------------------------------------------------------------------------

extern "C" void kernel_launch(void* const* d_in, const int* in_sizes, int n_in,
                              void* d_out, int out_size, void* d_ws, size_t ws_size,
                              hipStream_t stream) {
    const float* x        = (const float*)d_in[0];
    const float* enc_w1   = (const float*)d_in[1];
    const float* enc_b1   = (const float*)d_in[2];
    const float* res_w    = (const float*)d_in[3];
    const float* res_b    = (const float*)d_in[4];
    const float* res_g    = (const float*)d_in[5];
    const float* res_beta = (const float*)d_in[6];
    const float* enc_w2   = (const float*)d_in[7];
    const float* enc_b2   = (const float*)d_in[8];
    const float* emb      = (const float*)d_in[9];

    float* out = (float*)d_out;

    // workspace layout
    float* h  = (float*)d_ws;            // B*512 f32 (32MB), reused after enc2
    float* tz = h + (size_t)B_ * DENC_;  // B*768 f32 (48MB): t then z
    // VQ scratch overlapping h (dead after enc2):
    float* se    = h;                                        // 2048
    float* sz    = h + 2048;                                 // ROWS_
    int*   idxw  = (int*)(h + 2048 + (size_t)ROWS_);         // ROWS_
    int*   cnts  = (int*)(h + 2048 + 2 * (size_t)ROWS_);     // 2048
    float* lossacc = (float*)(cnts + NE_);                   // 1 (+pad)
    __bf16* Ehi  = (__bf16*)(h + 2048 + 2 * (size_t)ROWS_ + 2048 + 16);
    __bf16* Emid = Ehi + (size_t)NE_ * 64;
    __bf16* Elo  = Emid + (size_t)NE_ * 64;
    // pre-split weight planes (transposed [N][K]) after tz:
    __bf16* W1h = (__bf16*)(tz + (size_t)B_ * 768);   // 512*64 each
    __bf16* W1m = W1h + (size_t)DENC_ * IN_;
    __bf16* W1l = W1m + (size_t)DENC_ * IN_;
    __bf16* Wrh = W1l + (size_t)DENC_ * IN_;          // 512*512 each
    __bf16* Wrm = Wrh + (size_t)DENC_ * DENC_;
    __bf16* Wrl = Wrm + (size_t)DENC_ * DENC_;
    __bf16* W2h = Wrl + (size_t)DENC_ * DENC_;        // 768*512 each
    __bf16* W2m = W2h + (size_t)768 * DENC_;
    __bf16* W2l = W2m + (size_t)768 * DENC_;

    float* t = tz;
    float* z = tz;

    // pre-split weights (transposed bf16 planes)
    k_wsplit<<<(DENC_ * IN_ + 255) / 256, 256, 0, stream>>>(enc_w1, W1h, W1m, W1l, 6, DENC_, DENC_ * IN_);
    k_wsplit<<<(DENC_ * DENC_ + 255) / 256, 256, 0, stream>>>(res_w, Wrh, Wrm, Wrl, 9, DENC_, DENC_ * DENC_);
    k_wsplit<<<(768 * DENC_ + 255) / 256, 256, 0, stream>>>(enc_w2, W2h, W2m, W2l, 9, 768, 768 * DENC_);

    // encoder (MFMA path)
    k_gemm_mfma<<<dim3(DENC_ / 64, B_ / 128), 256, 0, stream>>>(x, W1h, W1m, W1l, enc_b1, h, DENC_, IN_);
    for (int r = 0; r < 2; ++r) {
        k_gemm_mfma<<<dim3(DENC_ / 64, B_ / 128), 256, 0, stream>>>(h, Wrh, Wrm, Wrl, res_b, t, DENC_, DENC_);
        k_lnrelu<<<B_ / 4, 256, 0, stream>>>(t, h, res_g, res_beta);
    }
    k_gemm_mfma<<<dim3(768 / 64, B_ / 128), 256, 0, stream>>>(h, W2h, W2m, W2l, enc_b2, z, 768, DENC_);

    // VQ
    hipMemsetAsync(cnts, 0, (NE_ + 16) * sizeof(int), stream);
    k_esplit_fast<<<NE_ / 4, 256, 0, stream>>>(emb, Ehi, Emid, Elo);
    k_esq<<<NE_ / 256, 256, 0, stream>>>(emb, se);
    k_rowsq<<<ROWS_ / 64, 256, 0, stream>>>(z, sz);
    k_distm<<<ROWS_ / 256, 256, 0, stream>>>(z, se, sz, Ehi, Emid, Elo,
                                             idxw, out + IDXF_OFF, lossacc, cnts);
    k_lossperp<<<1, 256, 0, stream>>>(lossacc, cnts, out);
    k_pinv<<<B_ / 4, 256, 0, stream>>>(x, emb, idxw, out + COEF_OFF, out + XHAT_OFF);
}

// Round 5
// 763.358 us; speedup vs baseline: 1.2040x; 1.2040x over previous
//
#include <hip/hip_runtime.h>
#include <math.h>

#define B_    16384
#define IN_   64
#define DENC_ 512
#define NE_   2048
#define P_    12
#define ROWS_ 196608      // B_*P_
#define BETA_ 0.25

// output layout (all float32, concatenated in return order)
#define XHAT_OFF 1
#define PERP_OFF 1048577   // 1 + 16384*64
#define IDXF_OFF 1048578
#define COEF_OFF 1245186   // IDXF_OFF + 196608

typedef __bf16 bf16x8 __attribute__((ext_vector_type(8)));
typedef float  f32x16 __attribute__((ext_vector_type(16)));

__device__ __forceinline__ void split3(float v, __bf16& h, __bf16& m, __bf16& l) {
    h = (__bf16)v;
    float r1 = v - (float)h;
    m = (__bf16)r1;
    float r2 = r1 - (float)m;
    l = (__bf16)r2;
}

// async global->LDS 16B per lane; dest = wave-uniform base + lane*16
__device__ __forceinline__ void gload_lds16(const void* g, void* l) {
    __builtin_amdgcn_global_load_lds((const __attribute__((address_space(1))) void*)g,
                                     (__attribute__((address_space(3))) void*)l, 16, 0, 0);
}

// ---------------------------------------------------------------------------
// Pre-split weights: W[K][N] f32 -> Wt planes [N][K] bf16 (hi/mid/lo).
// ---------------------------------------------------------------------------
__global__ void k_wsplit(const float* __restrict__ W,
                         __bf16* __restrict__ Wh, __bf16* __restrict__ Wm,
                         __bf16* __restrict__ Wl, int kshift, int N, int total) {
    int idx = blockIdx.x * 256 + threadIdx.x;
    if (idx < total) {
        int n = idx >> kshift;
        int k = idx & ((1 << kshift) - 1);
        float v = W[(size_t)k * N + n];
        __bf16 h, m, l;
        split3(v, h, m, l);
        Wh[idx] = h; Wm[idx] = m; Wl[idx] = l;
    }
}

// ---------------------------------------------------------------------------
// MFMA GEMM + bias (3-term split), double-buffered LDS + global_load_lds
// staging with swizzled SOURCE addresses (LDS layout identical to R3).
// One barrier per K-chunk; prefetch issued right after the barrier.
// ---------------------------------------------------------------------------
__global__ __launch_bounds__(256) void k_gemm_mfma(const float* __restrict__ A,
                                                   const __bf16* __restrict__ Bh,
                                                   const __bf16* __restrict__ Bm,
                                                   const __bf16* __restrict__ Bl,
                                                   const float* __restrict__ bias,
                                                   float* __restrict__ C,
                                                   int N, int K) {
    __shared__ __bf16 eS[2][3][64 * 64];   // 48 KB

    const int tid = threadIdx.x;
    const int w = tid >> 6, lane = tid & 63;
    const int r0 = blockIdx.y * 128 + w * 32;
    const int n0 = blockIdx.x * 64;
    const int lrow = lane & 31;
    const int half = lane >> 5;

    // staging source offsets (swizzled granule within each 128B row)
    const int cc0 = tid >> 3, qq = tid & 7;
    const int cc1 = cc0 + 32;
    const size_t off0 = (size_t)cc0 * K + (size_t)((qq ^ (cc0 & 7)) * 8);
    const size_t off1 = (size_t)cc1 * K + (size_t)((qq ^ (cc1 & 7)) * 8);
    const size_t nbase = (size_t)n0 * K;
    // wave-uniform LDS dest element offsets
    const int ld0 = w * 512;
    const int ld1 = 2048 + w * 512;

    f32x16 acc0, acc1;
#pragma unroll
    for (int i = 0; i < 16; ++i) { acc0[i] = 0.0f; acc1[i] = 0.0f; }

    // prologue: stage chunk 0 into buffer 0
    {
        const size_t b = nbase;
        gload_lds16(Bh + b + off0, &eS[0][0][ld0]);
        gload_lds16(Bh + b + off1, &eS[0][0][ld1]);
        gload_lds16(Bm + b + off0, &eS[0][1][ld0]);
        gload_lds16(Bm + b + off1, &eS[0][1][ld1]);
        gload_lds16(Bl + b + off0, &eS[0][2][ld0]);
        gload_lds16(Bl + b + off1, &eS[0][2][ld1]);
    }

    const int nch = K >> 6;
    for (int ch = 0; ch < nch; ++ch) {
        const int cur = ch & 1;
        __syncthreads();   // drains stage(ch) (issued a full compute phase ago)

        if (ch + 1 < nch) {
            const int nxt = cur ^ 1;
            const size_t b = nbase + (size_t)(ch + 1) * 64;
            gload_lds16(Bh + b + off0, &eS[nxt][0][ld0]);
            gload_lds16(Bh + b + off1, &eS[nxt][0][ld1]);
            gload_lds16(Bm + b + off0, &eS[nxt][1][ld0]);
            gload_lds16(Bm + b + off1, &eS[nxt][1][ld1]);
            gload_lds16(Bl + b + off0, &eS[nxt][2][ld0]);
            gload_lds16(Bl + b + off1, &eS[nxt][2][ld1]);
        }

        // A fragments for this chunk: split f32 rows in-register
        bf16x8 ah[4], am[4], al[4];
        {
            const float* ar = A + (size_t)(r0 + lrow) * K + ch * 64 + half * 8;
#pragma unroll
            for (int kc = 0; kc < 4; ++kc) {
                float4 u0 = *(const float4*)(ar + kc * 16);
                float4 u1 = *(const float4*)(ar + kc * 16 + 4);
                float v[8] = {u0.x, u0.y, u0.z, u0.w, u1.x, u1.y, u1.z, u1.w};
#pragma unroll
                for (int j = 0; j < 8; ++j) {
                    __bf16 hh, mm, ll;
                    split3(v[j], hh, mm, ll);
                    ah[kc][j] = hh; am[kc][j] = mm; al[kc][j] = ll;
                }
            }
        }

#pragma unroll
        for (int kc = 0; kc < 4; ++kc) {
            const int q = kc * 2 + half;
            const int g = (q ^ (lrow & 7)) * 8;
            bf16x8 b0h = *(const bf16x8*)(&eS[cur][0][lrow * 64 + g]);
            bf16x8 b0m = *(const bf16x8*)(&eS[cur][1][lrow * 64 + g]);
            bf16x8 b0l = *(const bf16x8*)(&eS[cur][2][lrow * 64 + g]);
            bf16x8 b1h = *(const bf16x8*)(&eS[cur][0][(lrow + 32) * 64 + g]);
            bf16x8 b1m = *(const bf16x8*)(&eS[cur][1][(lrow + 32) * 64 + g]);
            bf16x8 b1l = *(const bf16x8*)(&eS[cur][2][(lrow + 32) * 64 + g]);

            acc0 = __builtin_amdgcn_mfma_f32_32x32x16_bf16(ah[kc], b0h, acc0, 0, 0, 0);
            acc1 = __builtin_amdgcn_mfma_f32_32x32x16_bf16(ah[kc], b1h, acc1, 0, 0, 0);
            acc0 = __builtin_amdgcn_mfma_f32_32x32x16_bf16(ah[kc], b0m, acc0, 0, 0, 0);
            acc1 = __builtin_amdgcn_mfma_f32_32x32x16_bf16(ah[kc], b1m, acc1, 0, 0, 0);
            acc0 = __builtin_amdgcn_mfma_f32_32x32x16_bf16(am[kc], b0h, acc0, 0, 0, 0);
            acc1 = __builtin_amdgcn_mfma_f32_32x32x16_bf16(am[kc], b1h, acc1, 0, 0, 0);
            acc0 = __builtin_amdgcn_mfma_f32_32x32x16_bf16(ah[kc], b0l, acc0, 0, 0, 0);
            acc1 = __builtin_amdgcn_mfma_f32_32x32x16_bf16(ah[kc], b1l, acc1, 0, 0, 0);
            acc0 = __builtin_amdgcn_mfma_f32_32x32x16_bf16(am[kc], b0m, acc0, 0, 0, 0);
            acc1 = __builtin_amdgcn_mfma_f32_32x32x16_bf16(am[kc], b1m, acc1, 0, 0, 0);
            acc0 = __builtin_amdgcn_mfma_f32_32x32x16_bf16(al[kc], b0h, acc0, 0, 0, 0);
            acc1 = __builtin_amdgcn_mfma_f32_32x32x16_bf16(al[kc], b1h, acc1, 0, 0, 0);
        }
    }

    const int col0 = n0 + lrow, col1 = col0 + 32;
    const float bv0 = bias[col0], bv1 = bias[col1];
#pragma unroll
    for (int r = 0; r < 16; ++r) {
        int row = r0 + (r & 3) + 8 * (r >> 2) + 4 * half;
        C[(size_t)row * N + col0] = acc0[r] + bv0;
        C[(size_t)row * N + col1] = acc1[r] + bv1;
    }
}

// ---------------------------------------------------------------------------
// h = h + relu(layer_norm(t) * g + beta)
// ---------------------------------------------------------------------------
__global__ __launch_bounds__(256) void k_lnrelu(const float* __restrict__ t,
                                                float* __restrict__ h,
                                                const float* __restrict__ g,
                                                const float* __restrict__ beta) {
    const int tid = threadIdx.x;
    const int wv = tid >> 6, lane = tid & 63;
    const int row = blockIdx.x * 4 + wv;
    const float* tr = t + (size_t)row * DENC_;
    float* hr = h + (size_t)row * DENC_;

    float4 v0 = *(const float4*)(tr + lane * 4);
    float4 v1 = *(const float4*)(tr + 256 + lane * 4);

    float s = v0.x + v0.y + v0.z + v0.w + v1.x + v1.y + v1.z + v1.w;
#pragma unroll
    for (int m = 1; m < 64; m <<= 1) s += __shfl_xor(s, m);
    float mu = s / 512.0f;

    float d0x = v0.x - mu, d0y = v0.y - mu, d0z = v0.z - mu, d0w = v0.w - mu;
    float d1x = v1.x - mu, d1y = v1.y - mu, d1z = v1.z - mu, d1w = v1.w - mu;
    float vs = d0x * d0x + d0y * d0y + d0z * d0z + d0w * d0w +
               d1x * d1x + d1y * d1y + d1z * d1z + d1w * d1w;
#pragma unroll
    for (int m = 1; m < 64; m <<= 1) vs += __shfl_xor(vs, m);
    float var = vs / 512.0f;
    float rs = (float)(1.0 / sqrt((double)var + 1e-5));

    float4 g0 = *(const float4*)(g + lane * 4);
    float4 g1 = *(const float4*)(g + 256 + lane * 4);
    float4 b0 = *(const float4*)(beta + lane * 4);
    float4 b1 = *(const float4*)(beta + 256 + lane * 4);

    float4 h0 = *(float4*)(hr + lane * 4);
    float4 h1 = *(float4*)(hr + 256 + lane * 4);

    h0.x += fmaxf(d0x * rs * g0.x + b0.x, 0.0f);
    h0.y += fmaxf(d0y * rs * g0.y + b0.y, 0.0f);
    h0.z += fmaxf(d0z * rs * g0.z + b0.z, 0.0f);
    h0.w += fmaxf(d0w * rs * g0.w + b0.w, 0.0f);
    h1.x += fmaxf(d1x * rs * g1.x + b1.x, 0.0f);
    h1.y += fmaxf(d1y * rs * g1.y + b1.y, 0.0f);
    h1.z += fmaxf(d1z * rs * g1.z + b1.z, 0.0f);
    h1.w += fmaxf(d1w * rs * g1.w + b1.w, 0.0f);

    *(float4*)(hr + lane * 4) = h0;
    *(float4*)(hr + 256 + lane * 4) = h1;
}

// ---------------------------------------------------------------------------
// Codebook split (coalesced) + se (exact R3 association)
// ---------------------------------------------------------------------------
__global__ __launch_bounds__(256) void k_esplit_fast(const float* __restrict__ emb,
                                                     __bf16* __restrict__ Ehi,
                                                     __bf16* __restrict__ Emid,
                                                     __bf16* __restrict__ Elo) {
    const int wv = threadIdx.x >> 6, lane = threadIdx.x & 63;
    const int c = blockIdx.x * 4 + wv;
    float v = emb[(size_t)c * 64 + lane];
    __bf16 h, m, l;
    split3(v, h, m, l);
    Ehi[(size_t)c * 64 + lane] = h;
    Emid[(size_t)c * 64 + lane] = m;
    Elo[(size_t)c * 64 + lane] = l;
}

__global__ void k_esq(const float* __restrict__ emb, float* __restrict__ se) {
    int t = blockIdx.x * 256 + threadIdx.x;
    if (t < NE_) {
        float s = 0.0f;
        for (int k = 0; k < 64; ++k) {
            float v = emb[(size_t)t * 64 + k];
            s += v * v;
        }
        se[t] = s;
    }
}

// ---------------------------------------------------------------------------
// sz[row] = sum(z[row]^2)  (association unchanged)
// ---------------------------------------------------------------------------
__global__ __launch_bounds__(256) void k_rowsq(const float* __restrict__ z,
                                               float* __restrict__ sz) {
    const int tid = threadIdx.x;
    const int row = blockIdx.x * 64 + (tid >> 2);
    const int part = tid & 3;
    const float4* zp = (const float4*)(z + (size_t)row * 64) + part * 4;
    float s = 0.0f;
#pragma unroll
    for (int i = 0; i < 4; ++i) {
        float4 v = zp[i];
        s += v.x * v.x + v.y * v.y + v.z * v.z + v.w * v.w;
    }
    s += __shfl_xor(s, 1);
    s += __shfl_xor(s, 2);
    if (part == 0) sz[row] = s;
}

// ---------------------------------------------------------------------------
// MFMA distance + argmin: R3 dataflow (32 rows/wave, 112 VGPR class) +
// double-buffered LDS + global_load_lds staging + single barrier per chunk.
// Numerics identical to R1-R4: d = fmaf(-2,dot, sz+se), first-index ties.
// ---------------------------------------------------------------------------
__global__ __launch_bounds__(256) void k_distm(const float* __restrict__ z,
                                               const float* __restrict__ se,
                                               const float* __restrict__ sz,
                                               const __bf16* __restrict__ Ehi,
                                               const __bf16* __restrict__ Emid,
                                               const __bf16* __restrict__ Elo,
                                               int* __restrict__ idxw,
                                               float* __restrict__ idxf,
                                               float* __restrict__ lossacc,
                                               int* __restrict__ counts) {
    __shared__ __bf16 eS[2][3][64 * 64];   // 48 KB

    const int tid = threadIdx.x;
    const int w = tid >> 6, lane = tid & 63;
    const int r0 = blockIdx.x * 128 + w * 32;
    const int lrow = lane & 31;
    const int half = lane >> 5;

    // staging offsets (swizzled source granule; linear LDS dest)
    const int cc0 = tid >> 3, qq = tid & 7;
    const int cc1 = cc0 + 32;
    const int off0 = cc0 * 64 + (qq ^ (cc0 & 7)) * 8;
    const int off1 = cc1 * 64 + (qq ^ (cc1 & 7)) * 8;
    const int ld0 = w * 512;
    const int ld1 = 2048 + w * 512;

    // persistent A fragments (3-way split of z rows)
    bf16x8 ah[4], am[4], al[4];
    {
        const float* zr = z + (size_t)(r0 + lrow) * 64 + half * 8;
#pragma unroll
        for (int kc = 0; kc < 4; ++kc) {
            float4 u0 = *(const float4*)(zr + kc * 16);
            float4 u1 = *(const float4*)(zr + kc * 16 + 4);
            float v[8] = {u0.x, u0.y, u0.z, u0.w, u1.x, u1.y, u1.z, u1.w};
#pragma unroll
            for (int j = 0; j < 8; ++j) {
                __bf16 hh, mm, ll;
                split3(v[j], hh, mm, ll);
                ah[kc][j] = hh; am[kc][j] = mm; al[kc][j] = ll;
            }
        }
    }

    float szv[16];
#pragma unroll
    for (int r = 0; r < 16; ++r) {
        int rl = (r & 3) + 8 * (r >> 2) + 4 * half;
        szv[r] = sz[r0 + rl];
    }

    float bd[16];
    int bi[16];
#pragma unroll
    for (int r = 0; r < 16; ++r) { bd[r] = 1e30f; bi[r] = 0; }

    // prologue: stage chunk 0 into buffer 0
    gload_lds16(Ehi + off0, &eS[0][0][ld0]);
    gload_lds16(Ehi + off1, &eS[0][0][ld1]);
    gload_lds16(Emid + off0, &eS[0][1][ld0]);
    gload_lds16(Emid + off1, &eS[0][1][ld1]);
    gload_lds16(Elo + off0, &eS[0][2][ld0]);
    gload_lds16(Elo + off1, &eS[0][2][ld1]);

    for (int ch = 0; ch < 32; ++ch) {
        const int cur = ch & 1;
        __syncthreads();   // drains stage(ch); issued a full compute phase ago

        if (ch + 1 < 32) {
            const int nxt = cur ^ 1;
            const int b = (ch + 1) * 4096;
            gload_lds16(Ehi + b + off0, &eS[nxt][0][ld0]);
            gload_lds16(Ehi + b + off1, &eS[nxt][0][ld1]);
            gload_lds16(Emid + b + off0, &eS[nxt][1][ld0]);
            gload_lds16(Emid + b + off1, &eS[nxt][1][ld1]);
            gload_lds16(Elo + b + off0, &eS[nxt][2][ld0]);
            gload_lds16(Elo + b + off1, &eS[nxt][2][ld1]);
        }

        f32x16 acc0, acc1;
#pragma unroll
        for (int i = 0; i < 16; ++i) { acc0[i] = 0.0f; acc1[i] = 0.0f; }

#pragma unroll
        for (int kc = 0; kc < 4; ++kc) {
            const int q = kc * 2 + half;
            const int g = (q ^ (lrow & 7)) * 8;
            bf16x8 b0h = *(const bf16x8*)(&eS[cur][0][lrow * 64 + g]);
            bf16x8 b0m = *(const bf16x8*)(&eS[cur][1][lrow * 64 + g]);
            bf16x8 b0l = *(const bf16x8*)(&eS[cur][2][lrow * 64 + g]);
            bf16x8 b1h = *(const bf16x8*)(&eS[cur][0][(lrow + 32) * 64 + g]);
            bf16x8 b1m = *(const bf16x8*)(&eS[cur][1][(lrow + 32) * 64 + g]);
            bf16x8 b1l = *(const bf16x8*)(&eS[cur][2][(lrow + 32) * 64 + g]);

            acc0 = __builtin_amdgcn_mfma_f32_32x32x16_bf16(ah[kc], b0h, acc0, 0, 0, 0);
            acc1 = __builtin_amdgcn_mfma_f32_32x32x16_bf16(ah[kc], b1h, acc1, 0, 0, 0);
            acc0 = __builtin_amdgcn_mfma_f32_32x32x16_bf16(ah[kc], b0m, acc0, 0, 0, 0);
            acc1 = __builtin_amdgcn_mfma_f32_32x32x16_bf16(ah[kc], b1m, acc1, 0, 0, 0);
            acc0 = __builtin_amdgcn_mfma_f32_32x32x16_bf16(am[kc], b0h, acc0, 0, 0, 0);
            acc1 = __builtin_amdgcn_mfma_f32_32x32x16_bf16(am[kc], b1h, acc1, 0, 0, 0);
            acc0 = __builtin_amdgcn_mfma_f32_32x32x16_bf16(ah[kc], b0l, acc0, 0, 0, 0);
            acc1 = __builtin_amdgcn_mfma_f32_32x32x16_bf16(ah[kc], b1l, acc1, 0, 0, 0);
            acc0 = __builtin_amdgcn_mfma_f32_32x32x16_bf16(am[kc], b0m, acc0, 0, 0, 0);
            acc1 = __builtin_amdgcn_mfma_f32_32x32x16_bf16(am[kc], b1m, acc1, 0, 0, 0);
            acc0 = __builtin_amdgcn_mfma_f32_32x32x16_bf16(al[kc], b0h, acc0, 0, 0, 0);
            acc1 = __builtin_amdgcn_mfma_f32_32x32x16_bf16(al[kc], b1h, acc1, 0, 0, 0);
        }

        const int c0 = ch * 64;
        const float se0 = se[c0 + lrow];
        const float se1 = se[c0 + lrow + 32];
        const int   ci0 = c0 + lrow, ci1 = c0 + lrow + 32;
#pragma unroll
        for (int r = 0; r < 16; ++r) {
            float d0 = fmaf(-2.0f, acc0[r], szv[r] + se0);
            if (d0 < bd[r]) { bd[r] = d0; bi[r] = ci0; }
            float d1 = fmaf(-2.0f, acc1[r], szv[r] + se1);
            if (d1 < bd[r]) { bd[r] = d1; bi[r] = ci1; }
        }
    }

    // cross-lane argmin within each 32-lane half (lexicographic: d, then idx)
#pragma unroll
    for (int r = 0; r < 16; ++r) {
        float d = bd[r];
        int i = bi[r];
#pragma unroll
        for (int off = 1; off < 32; off <<= 1) {
            float od = __shfl_xor(d, off);
            int oi = __shfl_xor(i, off);
            if (od < d || (od == d && oi < i)) { d = od; i = oi; }
        }
        bd[r] = d; bi[r] = i;
    }

    if (lrow == 0) {
        float lsum = 0.0f;
#pragma unroll
        for (int r = 0; r < 16; ++r) {
            int rl = (r & 3) + 8 * (r >> 2) + 4 * half;
            int row = r0 + rl;
            idxw[row] = bi[r];
            idxf[row] = (float)bi[r];
            lsum += bd[r];
            atomicAdd(&counts[bi[r]], 1);
        }
        atomicAdd(lossacc, lsum);
    }
}

// ---------------------------------------------------------------------------
// loss (from accumulated dmin sum) + perplexity (from counts)
// ---------------------------------------------------------------------------
__global__ __launch_bounds__(256) void k_lossperp(const float* __restrict__ lossacc,
                                                  const int* __restrict__ counts,
                                                  float* __restrict__ out) {
    __shared__ double red[256];
    const int tid = threadIdx.x;

    double hsum = 0.0;
    for (int i = tid; i < NE_; i += 256) {
        float p = (float)counts[i] / 196608.0f;
        float lg = logf(p + 1e-10f);
        hsum += (double)(p * lg);
    }
    red[tid] = hsum;
    __syncthreads();
    for (int off = 128; off > 0; off >>= 1) {
        if (tid < off) red[tid] += red[tid + off];
        __syncthreads();
    }
    if (tid == 0) {
        out[PERP_OFF] = (float)exp(-red[0]);
        out[0] = (float)((double)lossacc[0] * (1.0 + BETA_) / ((double)ROWS_ * IN_));
    }
}

// ---------------------------------------------------------------------------
// per-block pinv least-squares: coeff + x_hat (dedup -> min-norm, f64 Cholesky)
// ---------------------------------------------------------------------------
__global__ __launch_bounds__(256) void k_pinv(const float* __restrict__ xin,
                                              const float* __restrict__ emb,
                                              const int* __restrict__ idxw,
                                              float* __restrict__ coeff,
                                              float* __restrict__ xhat) {
    __shared__ float aS[4][12][65];
    __shared__ float xS[4][64];
    __shared__ double GS[4][12][12];
    __shared__ double bS[4][12];
    __shared__ double uS[4][12];
    __shared__ float cS[4][12];

    const int tid = threadIdx.x;
    const int wv = tid >> 6, lane = tid & 63;
    const int b = blockIdx.x * 4 + wv;

    int my = 0;
    if (lane < 12) my = idxw[(size_t)b * 12 + lane];
    int id[12];
#pragma unroll
    for (int p = 0; p < 12; ++p) id[p] = __shfl(my, p);

    int rep = lane, mcnt = 1;
    if (lane < 12) {
        rep = -1;
        mcnt = 0;
        for (int q = 0; q < 12; ++q) {
            if (id[q] == id[lane]) {
                if (rep < 0) rep = q;
                mcnt++;
            }
        }
    }

#pragma unroll
    for (int p = 0; p < 12; ++p) aS[wv][p][lane] = emb[(size_t)id[p] * 64 + lane];
    xS[wv][lane] = xin[(size_t)b * 64 + lane];
    __syncthreads();

    for (int item = lane; item < 90; item += 64) {
        if (item < 78) {
            int j = 0, k = 0, c = item;
            for (j = 0; j < 12; ++j) {
                int cnt = 12 - j;
                if (c < cnt) { k = j + c; break; }
                c -= cnt;
            }
            double s = 0.0;
            for (int t = 0; t < 64; ++t) s += (double)aS[wv][j][t] * (double)aS[wv][k][t];
            GS[wv][j][k] = s;
            GS[wv][k][j] = s;
        } else {
            int j = item - 78;
            double s = 0.0;
            for (int t = 0; t < 64; ++t) s += (double)aS[wv][j][t] * (double)xS[wv][t];
            bS[wv][j] = s;
        }
    }
    __syncthreads();

    if (lane == 0) {
        for (int p = 0; p < 12; ++p) {
            int rp = -1;
            for (int q = 0; q < 12; ++q) {
                if (id[q] == id[p]) { rp = q; break; }
            }
            if (rp != p) {
                for (int q = 0; q < 12; ++q) {
                    GS[wv][p][q] = 0.0;
                    GS[wv][q][p] = 0.0;
                }
                GS[wv][p][p] = 1.0;
                bS[wv][p] = 0.0;
            }
        }
    }
    __syncthreads();

    for (int j = 0; j < 12; ++j) {
        if (lane == j) {
            double s = GS[wv][j][j];
            for (int k = 0; k < j; ++k) {
                double l = GS[wv][j][k];
                s -= l * l;
            }
            GS[wv][j][j] = sqrt(fmax(s, 1e-30));
        }
        __syncthreads();
        if (lane > j && lane < 12) {
            double s = GS[wv][lane][j];
            for (int k = 0; k < j; ++k) s -= GS[wv][lane][k] * GS[wv][j][k];
            GS[wv][lane][j] = s / GS[wv][j][j];
        }
        __syncthreads();
    }

    if (lane == 0) {
        double y[12];
        for (int i = 0; i < 12; ++i) {
            double s = bS[wv][i];
            for (int k = 0; k < i; ++k) s -= GS[wv][i][k] * y[k];
            y[i] = s / GS[wv][i][i];
        }
        for (int i = 11; i >= 0; --i) {
            double s = y[i];
            for (int k = i + 1; k < 12; ++k) s -= GS[wv][k][i] * uS[wv][k];
            uS[wv][i] = s / GS[wv][i][i];
        }
    }
    __syncthreads();

    if (lane < 12) {
        double c = uS[wv][rep] / (double)mcnt;
        coeff[(size_t)b * 12 + lane] = (float)c;
        cS[wv][lane] = (float)c;
    }
    __syncthreads();

    float s = 0.0f;
#pragma unroll
    for (int p = 0; p < 12; ++p) s += aS[wv][p][lane] * cS[wv][p];
    xhat[(size_t)b * 64 + lane] = s;
}

// ---------------------------------------------------------------------------

extern "C" void kernel_launch(void* const* d_in, const int* in_sizes, int n_in,
                              void* d_out, int out_size, void* d_ws, size_t ws_size,
                              hipStream_t stream) {
    const float* x        = (const float*)d_in[0];
    const float* enc_w1   = (const float*)d_in[1];
    const float* enc_b1   = (const float*)d_in[2];
    const float* res_w    = (const float*)d_in[3];
    const float* res_b    = (const float*)d_in[4];
    const float* res_g    = (const float*)d_in[5];
    const float* res_beta = (const float*)d_in[6];
    const float* enc_w2   = (const float*)d_in[7];
    const float* enc_b2   = (const float*)d_in[8];
    const float* emb      = (const float*)d_in[9];

    float* out = (float*)d_out;

    // workspace layout
    float* h  = (float*)d_ws;            // B*512 f32 (32MB), reused after enc2
    float* tz = h + (size_t)B_ * DENC_;  // B*768 f32 (48MB): t then z
    // VQ scratch overlapping h (dead after enc2):
    float* se    = h;                                        // 2048
    float* sz    = h + 2048;                                 // ROWS_
    int*   idxw  = (int*)(h + 2048 + (size_t)ROWS_);         // ROWS_
    int*   cnts  = (int*)(h + 2048 + 2 * (size_t)ROWS_);     // 2048
    float* lossacc = (float*)(cnts + NE_);                   // 1 (+pad)
    __bf16* Ehi  = (__bf16*)(h + 2048 + 2 * (size_t)ROWS_ + 2048 + 16);
    __bf16* Emid = Ehi + (size_t)NE_ * 64;
    __bf16* Elo  = Emid + (size_t)NE_ * 64;
    // pre-split weight planes (transposed [N][K]) after tz:
    __bf16* W1h = (__bf16*)(tz + (size_t)B_ * 768);   // 512*64 each
    __bf16* W1m = W1h + (size_t)DENC_ * IN_;
    __bf16* W1l = W1m + (size_t)DENC_ * IN_;
    __bf16* Wrh = W1l + (size_t)DENC_ * IN_;          // 512*512 each
    __bf16* Wrm = Wrh + (size_t)DENC_ * DENC_;
    __bf16* Wrl = Wrm + (size_t)DENC_ * DENC_;
    __bf16* W2h = Wrl + (size_t)DENC_ * DENC_;        // 768*512 each
    __bf16* W2m = W2h + (size_t)768 * DENC_;
    __bf16* W2l = W2m + (size_t)768 * DENC_;

    float* t = tz;
    float* z = tz;

    // pre-split weights (transposed bf16 planes)
    k_wsplit<<<(DENC_ * IN_ + 255) / 256, 256, 0, stream>>>(enc_w1, W1h, W1m, W1l, 6, DENC_, DENC_ * IN_);
    k_wsplit<<<(DENC_ * DENC_ + 255) / 256, 256, 0, stream>>>(res_w, Wrh, Wrm, Wrl, 9, DENC_, DENC_ * DENC_);
    k_wsplit<<<(768 * DENC_ + 255) / 256, 256, 0, stream>>>(enc_w2, W2h, W2m, W2l, 9, 768, 768 * DENC_);

    // encoder (MFMA path, double-buffered)
    k_gemm_mfma<<<dim3(DENC_ / 64, B_ / 128), 256, 0, stream>>>(x, W1h, W1m, W1l, enc_b1, h, DENC_, IN_);
    for (int r = 0; r < 2; ++r) {
        k_gemm_mfma<<<dim3(DENC_ / 64, B_ / 128), 256, 0, stream>>>(h, Wrh, Wrm, Wrl, res_b, t, DENC_, DENC_);
        k_lnrelu<<<B_ / 4, 256, 0, stream>>>(t, h, res_g, res_beta);
    }
    k_gemm_mfma<<<dim3(768 / 64, B_ / 128), 256, 0, stream>>>(h, W2h, W2m, W2l, enc_b2, z, 768, DENC_);

    // VQ
    hipMemsetAsync(cnts, 0, (NE_ + 16) * sizeof(int), stream);
    k_esplit_fast<<<NE_ / 4, 256, 0, stream>>>(emb, Ehi, Emid, Elo);
    k_esq<<<NE_ / 256, 256, 0, stream>>>(emb, se);
    k_rowsq<<<ROWS_ / 64, 256, 0, stream>>>(z, sz);
    k_distm<<<ROWS_ / 128, 256, 0, stream>>>(z, se, sz, Ehi, Emid, Elo,
                                             idxw, out + IDXF_OFF, lossacc, cnts);
    k_lossperp<<<1, 256, 0, stream>>>(lossacc, cnts, out);
    k_pinv<<<B_ / 4, 256, 0, stream>>>(x, emb, idxw, out + COEF_OFF, out + XHAT_OFF);
}